// Round 2
// baseline (68.985 us; speedup 1.0000x reference)
//
#include <hip/hip_runtime.h>
#include <limits.h>

// Problem constants (from the reference file)
#define BATCH 512
#define SEQ   8192
#define KLEN  8   // result_len
// n in [3,5]; pattern for n is the last n valid tokens; window starts at p;
// match valid iff p <= L - n - KLEN. Priority: n=5 > 4 > 3, FIRST (min p) match.

__global__ __launch_bounds__(1024)
void ngram_match_kernel(const int* __restrict__ num_tokens,      // [B]
                        const int* __restrict__ tokens,          // [B,S]
                        const int* __restrict__ mask,            // [B] bool as int32
                        int* __restrict__ out)                   // [B,K]
{
    const int b   = blockIdx.x;
    const int tid = threadIdx.x;
    const int L   = num_tokens[b];
    const long base = (long)b * SEQ;

    __shared__ int s_min[3];   // first-match position for n=3,4,5
    __shared__ int s_start;
    if (tid < 3) s_min[tid] = INT_MAX;
    __syncthreads();

    const int limit3 = L - 3 - KLEN;   // max valid p for n=3
    const int limit4 = L - 4 - KLEN;
    const int limit5 = L - 5 - KLEN;

    // Last-5 valid tokens (pattern). Only load entries that are in-range;
    // the per-position limit checks make unused dummies harmless.
    int pat0 = 0, pat1 = 0, pat2 = 0, pat3 = 0, pat4 = 0;
    if (limit3 >= 0) {            // L >= 11  -> L-3 >= 8, indices safe
        pat2 = tokens[base + L - 3];
        pat3 = tokens[base + L - 2];
        pat4 = tokens[base + L - 1];
        if (limit4 >= 0) pat1 = tokens[base + L - 4];
        if (limit5 >= 0) pat0 = tokens[base + L - 5];
    }

    int m3 = INT_MAX, m4 = INT_MAX, m5 = INT_MAX;

    // Each thread owns 4 consecutive positions per iteration; two aligned
    // int4 loads give the 8 tokens needed for windows p0..p0+3 (+4 lookahead).
    // Safe: p0 <= limit3 -> p0+7 <= L-4 < SEQ.
    for (int p0 = tid * 4; p0 <= limit3; p0 += (int)blockDim.x * 4) {
        const int4 va = *(const int4*)(tokens + base + p0);
        const int4 vb = *(const int4*)(tokens + base + p0 + 4);
        int w[8] = { va.x, va.y, va.z, va.w, vb.x, vb.y, vb.z, vb.w };
        #pragma unroll
        for (int j = 0; j < 4; ++j) {
            const int p = p0 + j;
            const bool q3 = (w[j]   == pat2) & (w[j+1] == pat3) & (w[j+2] == pat4)
                            & (p <= limit3);
            const bool q4 = (w[j]   == pat1) & (w[j+1] == pat2) & (w[j+2] == pat3)
                            & (w[j+3] == pat4) & (p <= limit4);
            const bool q5 = (w[j]   == pat0) & (w[j+1] == pat1) & (w[j+2] == pat2)
                            & (w[j+3] == pat3) & (w[j+4] == pat4) & (p <= limit5);
            if (q3) m3 = min(m3, p);
            if (q4) m4 = min(m4, p);
            if (q5) m5 = min(m5, p);
        }
    }

    if (m3 != INT_MAX) atomicMin(&s_min[0], m3);
    if (m4 != INT_MAX) atomicMin(&s_min[1], m4);
    if (m5 != INT_MAX) atomicMin(&s_min[2], m5);
    __syncthreads();

    if (tid == 0) {
        int start = -1;
        if      (s_min[2] != INT_MAX) start = s_min[2] + 5;  // longest n wins
        else if (s_min[1] != INT_MAX) start = s_min[1] + 4;
        else if (s_min[0] != INT_MAX) start = s_min[0] + 3;
        s_start = start;
    }
    __syncthreads();

    if (tid < KLEN) {
        const int start = s_start;
        int v = 0;
        if (start >= 0 && mask[b] != 0) v = tokens[base + start + tid];
        out[b * KLEN + tid] = v;   // always write: d_out is re-poisoned
    }
}

extern "C" void kernel_launch(void* const* d_in, const int* in_sizes, int n_in,
                              void* d_out, int out_size, void* d_ws, size_t ws_size,
                              hipStream_t stream) {
    const int* num_tokens = (const int*)d_in[0];   // [B] int32
    const int* token_ids  = (const int*)d_in[1];   // [B,S] int32
    const int* cmask      = (const int*)d_in[2];   // [B] bool canonicalized to int32
    int* out              = (int*)d_out;           // [B,K] int32

    ngram_match_kernel<<<BATCH, 1024, 0, stream>>>(num_tokens, token_ids, cmask, out);
}